// Round 11
// baseline (200.414 us; speedup 1.0000x reference)
//
#include <hip/hip_runtime.h>
#include <stdint.h>
#include <stddef.h>

// Problem: out[b,a,o] = sum_{i,j} h0[b,a,i] h1[b,a,j] T[a,i,j,o], h=concat(x,1)
// GEMM form: C[b,o] += G[b,k]*Tb[a,k,o]; main k=j*128+i (i,j<128); k=16384+c:
// G=h1[c]; k=16512+c: G=h0[c]; k=16640: G=1. 261 K-tiles of 64.
#define NA     4
#define DDIM   128
#define OUTD   128
#define BM     128
#define BN     128
#define NTILES 261
#define TILE_B 16384          // BN * 64 * 2B (16KB per K64-tile image)
#define OUT_ELEMS (4096 * NA * OUTD)   // 2,097,152 f32
#define NKS    4

typedef _Float16 f16;
typedef __attribute__((ext_vector_type(8)))  _Float16 f16x8;
typedef __attribute__((ext_vector_type(4)))  float    f32x4;

static const size_t TB_BYTES = (size_t)NA * NTILES * TILE_B;           // 17,104,896
static const size_t WS_NEED  = TB_BYTES + (size_t)NKS * OUT_ELEMS * 4; // ~50.7 MB

// ---------------------------------------------------------------------------
// Prep: T f32 -> Tb f16, per (a,tile) a 16KB image; unit v = w*128+col
// (w = k-octet 0..7) holds k = tile*64 + w*8 + e at output-col `col`.
// ---------------------------------------------------------------------------
__global__ __launch_bounds__(256) void prep_kernel(const float* __restrict__ T,
                                                   f16* __restrict__ Tb) {
    int blk  = blockIdx.x;            // a*NTILES + tile
    int a    = blk / NTILES;
    int tile = blk - a * NTILES;
    int t    = threadIdx.x;
    f16* base = Tb + (size_t)blk * (TILE_B / 2);
    #pragma unroll
    for (int u = 0; u < 4; ++u) {
        int v   = t + u * 256;
        int w   = v >> 7;
        int col = v & 127;
        f16x8 ov;
        #pragma unroll
        for (int e = 0; e < 8; ++e) {
            int k = tile * 64 + w * 8 + e;
            int i = -1, j = 0;
            if (k < 16384)       { i = k & 127;   j = k >> 7;    }
            else if (k < 16512)  { i = 128;       j = k - 16384; }
            else if (k < 16640)  { i = k - 16512; j = 128;       }
            else if (k == 16640) { i = 128;       j = 128;       }
            float val = 0.f;
            if (i >= 0) val = T[(((size_t)a * 129 + i) * 129 + j) * 128 + col];
            ov[e] = (f16)val;
        }
        *(f16x8*)(base + (size_t)v * 8) = ov;
    }
}

__device__ __forceinline__ f16x8 pack_f16x8(f32x4 a, f32x4 b) {
    f16x8 h;
    #pragma unroll
    for (int e = 0; e < 4; ++e) { h[e] = (f16)a[e]; h[e + 4] = (f16)b[e]; }
    return h;
}

// ---------------------------------------------------------------------------
// GEMM: round-10 structure (16x16x32 MFMA, 8 acc chains/wave, pure MFMA
// bursts, direct global->reg B double-buffer, barrier-free main loop) at
// DOUBLED occupancy: NKS=4 -> grid 512 = 2 blocks/CU = 16 waves/CU =
// 4 waves/SIMD (VGPR 80 <= 128 cap). h1t = full 128-j window (32KB LDS).
// Block: 8 waves (2M x 4N), wave = 64 rows x 32 cols, acc[4][2].
// ---------------------------------------------------------------------------
template <bool ATOMIC>
__global__ __launch_bounds__(512, 4) void gemm_kernel(const float* __restrict__ x0,
                                                      const float* __restrict__ x1,
                                                      const f16* __restrict__ Tb,
                                                      float* __restrict__ dst) {
    __shared__ __align__(16) f16 h1t[128 * 128];    // 32KB: h1t[j*128+row]

    int bid = blockIdx.x;             // 512 blocks = 8 XCD x 64
    int xcd = bid & 7, idx = bid >> 3;
    int pair = xcd * 2 + (idx >> 5);  // 16 (a,ks) pairs, 2 per XCD (2MB Tb/XCD)
    int mt  = idx & 31;
    int a   = pair & 3;
    int ks  = pair >> 2;

    int t    = threadIdx.x;
    int lane = t & 63, wid = t >> 6;
    int wm   = wid >> 2, wn = wid & 3;     // 2M x 4N
    int l15  = lane & 15, g = lane >> 4;   // 16x16 frag: row/col=l15, k-octet=g
    int b0   = mt * BM;

    const char* tbb = (const char*)Tb + (size_t)a * NTILES * TILE_B;

    // ---- one-time h1 full window -> LDS transposed ----
    {
        int row = t & 127, part = t >> 7;            // 4 parts x 32 j
        const float* x1r = x1 + ((size_t)(b0 + row) * NA + a) * DDIM + part * 32;
        #pragma unroll
        for (int q = 0; q < 8; ++q) {
            f32x4 v = *(const f32x4*)(x1r + q * 4);
            #pragma unroll
            for (int e = 0; e < 4; ++e)
                h1t[(part * 32 + q * 4 + e) * 128 + row] = (f16)v[e];
        }
    }
    // ---- one-time h0 -> registers: h0r[mf][par][s], window i=par*64+s*32+g*8 ----
    f16x8 h0r[4][2][2];
    #pragma unroll
    for (int mf = 0; mf < 4; ++mf) {
        int row = b0 + wm * 64 + mf * 16 + l15;
        const float* x0r = x0 + ((size_t)row * NA + a) * DDIM;
        #pragma unroll
        for (int par = 0; par < 2; ++par)
            #pragma unroll
            for (int s = 0; s < 2; ++s) {
                int ib = par * 64 + s * 32 + g * 8;
                h0r[mf][par][s] = pack_f16x8(*(const f32x4*)(x0r + ib),
                                             *(const f32x4*)(x0r + ib + 4));
            }
    }
    __syncthreads();   // h1t visible; only barrier in the kernel

    // per-lane B fragment base: frag(nf,s) at ((s*4+g)*128 + wn*32+nf*16+l15)*16
    const char* bp = tbb + (size_t)(ks * 64) * TILE_B + ((size_t)g * 128 + wn * 32 + l15) * 16;
    #define BFOFF(nf, s) ((s) * 8192 + (nf) * 256)

    f16x8 bA[4], bB[4];
    #pragma unroll
    for (int nf = 0; nf < 2; ++nf)
        #pragma unroll
        for (int s = 0; s < 2; ++s) {
            bA[nf * 2 + s] = *(const f16x8*)(bp + BFOFF(nf, s));
            bB[nf * 2 + s] = *(const f16x8*)(bp + TILE_B + BFOFF(nf, s));
        }

    f32x4 acc[4][2];
    #pragma unroll
    for (int mf = 0; mf < 4; ++mf)
        #pragma unroll
        for (int nf = 0; nf < 2; ++nf) acc[mf][nf] = (f32x4)0.f;

    // ---- main loop: 32 j's = 32 tile pairs, barrier-free ----
    #pragma unroll 1
    for (int p = 0; p < 32; ++p) {
        int jg = ks * 32 + p;
        f16 h1v[4];
        #pragma unroll
        for (int mf = 0; mf < 4; ++mf)
            h1v[mf] = h1t[jg * 128 + wm * 64 + mf * 16 + l15];

        // build ALL 16 A-frags up front (pure VALU cluster)
        f16x8 af0[4][2], af1[4][2];
        #pragma unroll
        for (int mf = 0; mf < 4; ++mf)
            #pragma unroll
            for (int s = 0; s < 2; ++s) {
                af0[mf][s] = h0r[mf][0][s] * h1v[mf];
                af1[mf][s] = h0r[mf][1][s] * h1v[mf];
            }

        // tile 2p (i-half 0): pure 16-MFMA burst
        #pragma unroll
        for (int s = 0; s < 2; ++s)
            #pragma unroll
            for (int nf = 0; nf < 2; ++nf)
                #pragma unroll
                for (int mf = 0; mf < 4; ++mf)
                    acc[mf][nf] = __builtin_amdgcn_mfma_f32_16x16x32_f16(
                        af0[mf][s], bA[nf * 2 + s], acc[mf][nf], 0, 0, 0);
        {   // prefetch tile 2p+2 into bA
            int nxt = 2 * p + 2; if (nxt > 63) nxt = 63;
            const char* q = bp + (size_t)nxt * TILE_B;
            #pragma unroll
            for (int nf = 0; nf < 2; ++nf)
                #pragma unroll
                for (int s = 0; s < 2; ++s)
                    bA[nf * 2 + s] = *(const f16x8*)(q + BFOFF(nf, s));
        }
        // tile 2p+1 (i-half 1): pure 16-MFMA burst
        #pragma unroll
        for (int s = 0; s < 2; ++s)
            #pragma unroll
            for (int nf = 0; nf < 2; ++nf)
                #pragma unroll
                for (int mf = 0; mf < 4; ++mf)
                    acc[mf][nf] = __builtin_amdgcn_mfma_f32_16x16x32_f16(
                        af1[mf][s], bB[nf * 2 + s], acc[mf][nf], 0, 0, 0);
        {   // prefetch tile 2p+3 into bB
            int nxt = 2 * p + 3; if (nxt > 63) nxt = 63;
            const char* q = bp + (size_t)nxt * TILE_B;
            #pragma unroll
            for (int nf = 0; nf < 2; ++nf)
                #pragma unroll
                for (int s = 0; s < 2; ++s)
                    bB[nf * 2 + s] = *(const f16x8*)(q + BFOFF(nf, s));
        }
    }

    // ---- correction tail: ks0->256 (j-corr lo), ks1->257 (j-corr hi),
    //      ks2->{258 i-corr lo, 260 const}, ks3->259 (i-corr hi) ----
    int ncorr = (ks == 2) ? 2 : 1;
    for (int tt = 0; tt < ncorr; ++tt) {
        int tile;
        if      (ks == 0) tile = 256;
        else if (ks == 1) tile = 257;
        else if (ks == 2) tile = (tt == 0) ? 258 : 260;
        else              tile = 259;
        const char* q = tbb + (size_t)tile * TILE_B + ((size_t)g * 128 + wn * 32 + l15) * 16;
        f16x8 bt[4];
        #pragma unroll
        for (int nf = 0; nf < 2; ++nf)
            #pragma unroll
            for (int s = 0; s < 2; ++s)
                bt[nf * 2 + s] = *(const f16x8*)(q + BFOFF(nf, s));

        #pragma unroll
        for (int s = 0; s < 2; ++s)
            #pragma unroll
            for (int mf = 0; mf < 4; ++mf) {
                int row = wm * 64 + mf * 16 + l15;
                f16x8 af;
                if (tile == 256 || tile == 257) {        // j-corr: G=h1[cb+c]
                    int cb = (tile == 257) ? 64 : 0;
                    #pragma unroll
                    for (int e = 0; e < 8; ++e)
                        af[e] = h1t[(cb + s * 32 + g * 8 + e) * 128 + row];
                } else if (tile == 258) {                // i-corr lo: G=h0[c]
                    af = h0r[mf][0][s];
                } else if (tile == 259) {                // i-corr hi
                    af = h0r[mf][1][s];
                } else {                                 // 260: G=1 at k_local 0
                    af = (f16x8)(f16)0.f;
                    if (s == 0 && g == 0) af[0] = (f16)1.f;
                }
                #pragma unroll
                for (int nf = 0; nf < 2; ++nf)
                    acc[mf][nf] = __builtin_amdgcn_mfma_f32_16x16x32_f16(
                        af, bt[nf * 2 + s], acc[mf][nf], 0, 0, 0);
            }
    }

    // ---- epilogue: 16x16 C/D layout col=lane&15, row=(lane>>4)*4+r ----
    float* base = ATOMIC ? dst : dst + (size_t)ks * OUT_ELEMS;
    #pragma unroll
    for (int mf = 0; mf < 4; ++mf)
        #pragma unroll
        for (int nf = 0; nf < 2; ++nf)
            #pragma unroll
            for (int r = 0; r < 4; ++r) {
                int orow = b0 + wm * 64 + mf * 16 + g * 4 + r;
                int ocol = wn * 32 + nf * 16 + l15;
                size_t off = ((size_t)orow * NA + a) * OUTD + ocol;
                if (ATOMIC) unsafeAtomicAdd(&base[off], acc[mf][nf][r]);
                else        base[off] = acc[mf][nf][r];
            }
    #undef BFOFF
}

// ---------------------------------------------------------------------------
// Reduce: out = P0 + P1 + P2 + P3 (f32x4 vectorized)
// ---------------------------------------------------------------------------
__global__ __launch_bounds__(256) void reduce_kernel(const float* __restrict__ P,
                                                     float* __restrict__ out) {
    int i = blockIdx.x * 256 + threadIdx.x;     // 524288 vec4 elems
    f32x4 s = ((const f32x4*)P)[i];
    #pragma unroll
    for (int k = 1; k < NKS; ++k)
        s += ((const f32x4*)(P + (size_t)k * OUT_ELEMS))[i];
    ((f32x4*)out)[i] = s;
}

// ---------------------------------------------------------------------------
// Fallback (ws too small): naive but correct f32 kernel.
// ---------------------------------------------------------------------------
__global__ __launch_bounds__(128) void fallback_kernel(const float* __restrict__ x0,
                                                       const float* __restrict__ x1,
                                                       const float* __restrict__ T,
                                                       float* __restrict__ out) {
    int ba = blockIdx.x;
    int b = ba >> 2, a = ba & 3;
    int o = threadIdx.x;
    const float* h0 = x0 + ((size_t)b * NA + a) * DDIM;
    const float* h1 = x1 + ((size_t)b * NA + a) * DDIM;
    float acc = 0.f;
    for (int i = 0; i < 129; ++i) {
        float h0i = (i < 128) ? h0[i] : 1.f;
        const float* Trow = T + (((size_t)a * 129 + i) * 129) * 128 + o;
        float part = 0.f;
        for (int j = 0; j < 129; ++j) {
            float h1j = (j < 128) ? h1[j] : 1.f;
            part += h1j * Trow[(size_t)j * 128];
        }
        acc += h0i * part;
    }
    out[((size_t)b * NA + a) * OUTD + o] = acc;
}

extern "C" void kernel_launch(void* const* d_in, const int* in_sizes, int n_in,
                              void* d_out, int out_size, void* d_ws, size_t ws_size,
                              hipStream_t stream) {
    const float* x0 = (const float*)d_in[0];
    const float* x1 = (const float*)d_in[1];
    const float* T  = (const float*)d_in[2];
    float* out = (float*)d_out;

    if (ws_size < TB_BYTES) {
        fallback_kernel<<<4096 * NA, 128, 0, stream>>>(x0, x1, T, out);
        return;
    }

    f16* Tb = (f16*)d_ws;
    prep_kernel<<<NA * NTILES, 256, 0, stream>>>(T, Tb);

    if (ws_size >= WS_NEED) {
        float* P = (float*)((char*)d_ws + TB_BYTES);
        gemm_kernel<false><<<512, 512, 0, stream>>>(x0, x1, Tb, P);
        reduce_kernel<<<OUT_ELEMS / 4 / 256, 256, 0, stream>>>(P, out);
    } else {
        hipMemsetAsync(d_out, 0, (size_t)out_size * sizeof(float), stream);
        gemm_kernel<true><<<512, 512, 0, stream>>>(x0, x1, Tb, out);
    }
}

// Round 12
// 94.891 us; speedup vs baseline: 2.1120x; 2.1120x over previous
//
#include <hip/hip_runtime.h>
#include <stdint.h>
#include <stddef.h>

// Problem: out[b,a,o] = sum_{i,j} h0[b,a,i] h1[b,a,j] T[a,i,j,o], h=concat(x,1)
// GEMM form: C[b,o] += G[b,k]*Tb[a,k,o]; main k=j*128+i (i,j<128); k=16384+c:
// G=h1[c]; k=16512+c: G=h0[c]; k=16640: G=1. 261 K-tiles of 64.
#define NA     4
#define DDIM   128
#define OUTD   128
#define BM     128
#define NTILES 261
#define TILE_B 16384          // 128 cols * 64 k * 2B (16KB per K64-tile image)
#define OUT_ELEMS (4096 * NA * OUTD)   // 2,097,152 f32
#define NKS    4              // (i-half, j-half) split -> 4 partials

typedef _Float16 f16;
typedef __attribute__((ext_vector_type(8)))  _Float16 f16x8;
typedef __attribute__((ext_vector_type(4)))  float    f32x4;

static const size_t TB_BYTES = (size_t)NA * NTILES * TILE_B;           // 17,104,896
static const size_t WS_NEED  = TB_BYTES + (size_t)NKS * OUT_ELEMS * 4; // ~50.7 MB

// ---------------------------------------------------------------------------
// Prep: T f32 -> Tb f16, per (a,tile) a 16KB image; unit v = w*128+col
// (w = k-octet 0..7) holds k = tile*64 + w*8 + e at output-col `col`.
// ---------------------------------------------------------------------------
__global__ __launch_bounds__(256) void prep_kernel(const float* __restrict__ T,
                                                   f16* __restrict__ Tb) {
    int blk  = blockIdx.x;            // a*NTILES + tile
    int a    = blk / NTILES;
    int tile = blk - a * NTILES;
    int t    = threadIdx.x;
    f16* base = Tb + (size_t)blk * (TILE_B / 2);
    #pragma unroll
    for (int u = 0; u < 4; ++u) {
        int v   = t + u * 256;
        int w   = v >> 7;
        int col = v & 127;
        f16x8 ov;
        #pragma unroll
        for (int e = 0; e < 8; ++e) {
            int k = tile * 64 + w * 8 + e;
            int i = -1, j = 0;
            if (k < 16384)       { i = k & 127;   j = k >> 7;    }
            else if (k < 16512)  { i = 128;       j = k - 16384; }
            else if (k < 16640)  { i = k - 16512; j = 128;       }
            else if (k == 16640) { i = 128;       j = 128;       }
            float val = 0.f;
            if (i >= 0) val = T[(((size_t)a * 129 + i) * 129 + j) * 128 + col];
            ov[e] = (f16)val;
        }
        *(f16x8*)(base + (size_t)v * 8) = ov;
    }
}

__device__ __forceinline__ f16x8 pack_f16x8(f32x4 a, f32x4 b) {
    f16x8 h;
    #pragma unroll
    for (int e = 0; e < 4; ++e) { h[e] = (f16)a[e]; h[e + 4] = (f16)b[e]; }
    return h;
}

// ---------------------------------------------------------------------------
// GEMM, round 12: K split by BOTH i-half and j-half -> per-block register
// footprint shrinks so 3-4 waves/SIMD fit WITHOUT spill (round-11 lesson).
// Block: 4 waves (2M x 2N), wave = 64 rows x 32 cols, 16x16x32 MFMA,
// 8 acc chains/wave. h0r[4][2] = 32 VGPR (i-half is block-constant),
// B frags 4/j double-buffered (32 VGPR), acc 32. ~130 unified regs,
// launch_bounds(256,3) cap 170 -> spill-impossible.
// Grid 1024 = 4 blocks/CU nominal. Class (a,ihalf,jks) XCD-resident.
// Corrections: (i0,j0)->{256,258}, (i0,j1)->{257}, (i1,j0)->{259}, (i1,j1)->{260}.
// ---------------------------------------------------------------------------
template <bool ATOMIC>
__global__ __launch_bounds__(256, 3) void gemm_kernel(const float* __restrict__ x0,
                                                      const float* __restrict__ x1,
                                                      const f16* __restrict__ Tb,
                                                      float* __restrict__ dst) {
    __shared__ __align__(16) f16 h1t[64 * 128];     // 16KB: h1t[c][row], c = j - jb

    int bid = blockIdx.x;             // 1024 = 8 xcd * 128
    int xcd = bid & 7, idx = bid >> 3;
    int cls = xcd * 2 + (idx >> 6);   // 16 classes, 2 per XCD (L2-resident streams)
    int sub = idx & 63;
    int mt  = sub >> 1;
    int nsel = sub & 1;               // which 64-col half of OUT
    int a     = cls & 3;
    int ihalf = (cls >> 2) & 1;
    int jks   = cls >> 3;
    int b0 = mt * BM;
    int jb = jks * 64;

    int t    = threadIdx.x;
    int lane = t & 63, wid = t >> 6;
    int wm   = wid >> 1, wn = wid & 1;     // 2M x 2N
    int l15  = lane & 15, g = lane >> 4;   // 16x16 frag: row/col=l15, k-octet=g

    const char* tbb = (const char*)Tb + (size_t)a * NTILES * TILE_B;

    // ---- one-time h1 window (64 j, base jb) -> LDS transposed ----
    {
        int row = t & 127, part = t >> 7;            // 2 parts x 32 c
        const float* x1r = x1 + ((size_t)(b0 + row) * NA + a) * DDIM + jb + part * 32;
        #pragma unroll
        for (int q = 0; q < 8; ++q) {
            f32x4 v = *(const f32x4*)(x1r + q * 4);
            #pragma unroll
            for (int e = 0; e < 4; ++e)
                h1t[(part * 32 + q * 4 + e) * 128 + row] = (f16)v[e];
        }
    }
    // ---- one-time h0 -> registers: h0r[mf][s], i = ihalf*64 + s*32 + g*8 ----
    f16x8 h0r[4][2];
    #pragma unroll
    for (int mf = 0; mf < 4; ++mf) {
        int row = b0 + wm * 64 + mf * 16 + l15;
        const float* x0r = x0 + ((size_t)row * NA + a) * DDIM + ihalf * 64;
        #pragma unroll
        for (int s = 0; s < 2; ++s) {
            int ib = s * 32 + g * 8;
            h0r[mf][s] = pack_f16x8(*(const f32x4*)(x0r + ib),
                                    *(const f32x4*)(x0r + ib + 4));
        }
    }
    __syncthreads();   // h1t visible; only barrier in the kernel

    // per-lane B base: col = nsel*64 + wn*32 + nf*16 + l15; octet = s*4+g
    const char* bp = tbb + ((size_t)g * 128 + nsel * 64 + wn * 32 + l15) * 16;
    #define BFOFF(nf, s) ((s) * 8192 + (nf) * 256)
    // main tile for j-index p (p in [0,64)): tile = 2*(jb+p) + ihalf
    #define TADR(p) (bp + (size_t)(2 * (jb + (p)) + ihalf) * TILE_B)

    f16x8 bA[4], bB[4];   // [nf*2+s], double-buffered over j parity
    {
        const char* q0 = TADR(0);
        const char* q1 = TADR(1);
        #pragma unroll
        for (int nf = 0; nf < 2; ++nf)
            #pragma unroll
            for (int s = 0; s < 2; ++s) {
                bA[nf * 2 + s] = *(const f16x8*)(q0 + BFOFF(nf, s));
                bB[nf * 2 + s] = *(const f16x8*)(q1 + BFOFF(nf, s));
            }
    }

    f32x4 acc[4][2];
    #pragma unroll
    for (int mf = 0; mf < 4; ++mf)
        #pragma unroll
        for (int nf = 0; nf < 2; ++nf) acc[mf][nf] = (f32x4)0.f;

    // ---- main loop: 64 j's as 32 pairs, barrier-free ----
    #pragma unroll 1
    for (int q = 0; q < 32; ++q) {
        int p0 = 2 * q, p1 = 2 * q + 1;
        f16 h1v0[4], h1v1[4];
        #pragma unroll
        for (int mf = 0; mf < 4; ++mf) {
            int row = wm * 64 + mf * 16 + l15;
            h1v0[mf] = h1t[p0 * 128 + row];
            h1v1[mf] = h1t[p1 * 128 + row];
        }

        // j = jb+p0 : 16-MFMA cluster from bA
        __builtin_amdgcn_s_setprio(1);
        #pragma unroll
        for (int s = 0; s < 2; ++s)
            #pragma unroll
            for (int mf = 0; mf < 4; ++mf) {
                f16x8 af = h0r[mf][s] * h1v0[mf];
                #pragma unroll
                for (int nf = 0; nf < 2; ++nf)
                    acc[mf][nf] = __builtin_amdgcn_mfma_f32_16x16x32_f16(
                        af, bA[nf * 2 + s], acc[mf][nf], 0, 0, 0);
            }
        __builtin_amdgcn_s_setprio(0);
        {   // prefetch j-pair slot p0+2 into bA
            int np = p0 + 2; if (np > 63) np = 63;
            const char* qq = TADR(np);
            #pragma unroll
            for (int nf = 0; nf < 2; ++nf)
                #pragma unroll
                for (int s = 0; s < 2; ++s)
                    bA[nf * 2 + s] = *(const f16x8*)(qq + BFOFF(nf, s));
        }

        // j = jb+p1 : 16-MFMA cluster from bB
        __builtin_amdgcn_s_setprio(1);
        #pragma unroll
        for (int s = 0; s < 2; ++s)
            #pragma unroll
            for (int mf = 0; mf < 4; ++mf) {
                f16x8 af = h0r[mf][s] * h1v1[mf];
                #pragma unroll
                for (int nf = 0; nf < 2; ++nf)
                    acc[mf][nf] = __builtin_amdgcn_mfma_f32_16x16x32_f16(
                        af, bB[nf * 2 + s], acc[mf][nf], 0, 0, 0);
            }
        __builtin_amdgcn_s_setprio(0);
        {   // prefetch j-pair slot p1+2 into bB
            int np = p1 + 2; if (np > 63) np = 63;
            const char* qq = TADR(np);
            #pragma unroll
            for (int nf = 0; nf < 2; ++nf)
                #pragma unroll
                for (int s = 0; s < 2; ++s)
                    bB[nf * 2 + s] = *(const f16x8*)(qq + BFOFF(nf, s));
        }
    }

    // ---- correction tail per class ----
    int ct0, ct1, ncorr;
    if (ihalf == 0 && jks == 0)      { ct0 = 256; ct1 = 258; ncorr = 2; }
    else if (ihalf == 0 && jks == 1) { ct0 = 257; ct1 = 0;   ncorr = 1; }
    else if (ihalf == 1 && jks == 0) { ct0 = 259; ct1 = 0;   ncorr = 1; }
    else                             { ct0 = 260; ct1 = 0;   ncorr = 1; }
    for (int cc = 0; cc < ncorr; ++cc) {
        int tile = (cc == 0) ? ct0 : ct1;
        const char* qq = tbb + (size_t)tile * TILE_B
                       + ((size_t)g * 128 + nsel * 64 + wn * 32 + l15) * 16;
        f16x8 bt[4];
        #pragma unroll
        for (int nf = 0; nf < 2; ++nf)
            #pragma unroll
            for (int s = 0; s < 2; ++s)
                bt[nf * 2 + s] = *(const f16x8*)(qq + BFOFF(nf, s));

        #pragma unroll
        for (int s = 0; s < 2; ++s)
            #pragma unroll
            for (int mf = 0; mf < 4; ++mf) {
                int row = wm * 64 + mf * 16 + l15;
                f16x8 af;
                if (tile == 256 || tile == 257) {        // j-corr: G = h1[jb + c]
                    #pragma unroll
                    for (int e = 0; e < 8; ++e)
                        af[e] = h1t[(s * 32 + g * 8 + e) * 128 + row];
                } else if (tile == 258 || tile == 259) { // i-corr: G = h0[ihalf*64 + c]
                    af = h0r[mf][s];
                } else {                                 // 260: G = 1 at k_local 0
                    af = (f16x8)(f16)0.f;
                    if (s == 0 && g == 0) af[0] = (f16)1.f;
                }
                #pragma unroll
                for (int nf = 0; nf < 2; ++nf)
                    acc[mf][nf] = __builtin_amdgcn_mfma_f32_16x16x32_f16(
                        af, bt[nf * 2 + s], acc[mf][nf], 0, 0, 0);
            }
    }

    // ---- epilogue: 16x16 C/D layout col=lane&15, row=(lane>>4)*4+r ----
    int clsk = ihalf * 2 + jks;
    float* base = ATOMIC ? dst : dst + (size_t)clsk * OUT_ELEMS;
    #pragma unroll
    for (int mf = 0; mf < 4; ++mf)
        #pragma unroll
        for (int nf = 0; nf < 2; ++nf)
            #pragma unroll
            for (int r = 0; r < 4; ++r) {
                int orow = b0 + wm * 64 + mf * 16 + g * 4 + r;
                int ocol = nsel * 64 + wn * 32 + nf * 16 + l15;
                size_t off = ((size_t)orow * NA + a) * OUTD + ocol;
                if (ATOMIC) unsafeAtomicAdd(&base[off], acc[mf][nf][r]);
                else        base[off] = acc[mf][nf][r];
            }
    #undef BFOFF
    #undef TADR
}

// ---------------------------------------------------------------------------
// Reduce: out = P0 + P1 + P2 + P3 (f32x4 vectorized)
// ---------------------------------------------------------------------------
__global__ __launch_bounds__(256) void reduce_kernel(const float* __restrict__ P,
                                                     float* __restrict__ out) {
    int i = blockIdx.x * 256 + threadIdx.x;     // 524288 vec4 elems
    f32x4 s = ((const f32x4*)P)[i];
    #pragma unroll
    for (int k = 1; k < NKS; ++k)
        s += ((const f32x4*)(P + (size_t)k * OUT_ELEMS))[i];
    ((f32x4*)out)[i] = s;
}

// ---------------------------------------------------------------------------
// Fallback (ws too small): naive but correct f32 kernel.
// ---------------------------------------------------------------------------
__global__ __launch_bounds__(128) void fallback_kernel(const float* __restrict__ x0,
                                                       const float* __restrict__ x1,
                                                       const float* __restrict__ T,
                                                       float* __restrict__ out) {
    int ba = blockIdx.x;
    int b = ba >> 2, a = ba & 3;
    int o = threadIdx.x;
    const float* h0 = x0 + ((size_t)b * NA + a) * DDIM;
    const float* h1 = x1 + ((size_t)b * NA + a) * DDIM;
    float acc = 0.f;
    for (int i = 0; i < 129; ++i) {
        float h0i = (i < 128) ? h0[i] : 1.f;
        const float* Trow = T + (((size_t)a * 129 + i) * 129) * 128 + o;
        float part = 0.f;
        for (int j = 0; j < 129; ++j) {
            float h1j = (j < 128) ? h1[j] : 1.f;
            part += h1j * Trow[(size_t)j * 128];
        }
        acc += h0i * part;
    }
    out[((size_t)b * NA + a) * OUTD + o] = acc;
}

extern "C" void kernel_launch(void* const* d_in, const int* in_sizes, int n_in,
                              void* d_out, int out_size, void* d_ws, size_t ws_size,
                              hipStream_t stream) {
    const float* x0 = (const float*)d_in[0];
    const float* x1 = (const float*)d_in[1];
    const float* T  = (const float*)d_in[2];
    float* out = (float*)d_out;

    if (ws_size < TB_BYTES) {
        fallback_kernel<<<4096 * NA, 128, 0, stream>>>(x0, x1, T, out);
        return;
    }

    f16* Tb = (f16*)d_ws;
    prep_kernel<<<NA * NTILES, 256, 0, stream>>>(T, Tb);

    if (ws_size >= WS_NEED) {
        float* P = (float*)((char*)d_ws + TB_BYTES);
        gemm_kernel<false><<<1024, 256, 0, stream>>>(x0, x1, Tb, P);
        reduce_kernel<<<OUT_ELEMS / 4 / 256, 256, 0, stream>>>(P, out);
    } else {
        hipMemsetAsync(d_out, 0, (size_t)out_size * sizeof(float), stream);
        gemm_kernel<true><<<1024, 256, 0, stream>>>(x0, x1, Tb, out);
    }
}

// Round 13
// 91.543 us; speedup vs baseline: 2.1893x; 1.0366x over previous
//
#include <hip/hip_runtime.h>
#include <stdint.h>
#include <stddef.h>

// Problem: out[b,a,o] = sum_{i,j} h0[b,a,i] h1[b,a,j] T[a,i,j,o], h=concat(x,1)
// GEMM form: C[b,o] += G[b,k]*Tb[a,k,o]; main k=j*128+i (i,j<128); k=16384+c:
// G=h1[c]; k=16512+c: G=h0[c]; k=16640: G=1. 261 K-tiles of 64.
#define NA     4
#define DDIM   128
#define OUTD   128
#define BM     256
#define NTILES 261
#define TILE_B 16384          // 128 cols * 64 k * 2B (16KB per K64-tile image)
#define OUT_ELEMS (4096 * NA * OUTD)   // 2,097,152 f32
#define NKS    4              // (i-half, j-half) split -> 4 partials

typedef _Float16 f16;
typedef __attribute__((ext_vector_type(8)))  _Float16 f16x8;
typedef __attribute__((ext_vector_type(4)))  float    f32x4;

static const size_t TB_BYTES = (size_t)NA * NTILES * TILE_B;           // 17,104,896
static const size_t WS_NEED  = TB_BYTES + (size_t)NKS * OUT_ELEMS * 4; // ~50.7 MB

// ---------------------------------------------------------------------------
// Prep: T f32 -> Tb f16, per (a,tile) a 16KB image; unit v = w*128+col
// (w = k-octet 0..7) holds k = tile*64 + w*8 + e at output-col `col`.
// ---------------------------------------------------------------------------
__global__ __launch_bounds__(256) void prep_kernel(const float* __restrict__ T,
                                                   f16* __restrict__ Tb) {
    int blk  = blockIdx.x;            // a*NTILES + tile
    int a    = blk / NTILES;
    int tile = blk - a * NTILES;
    int t    = threadIdx.x;
    f16* base = Tb + (size_t)blk * (TILE_B / 2);
    #pragma unroll
    for (int u = 0; u < 4; ++u) {
        int v   = t + u * 256;
        int w   = v >> 7;
        int col = v & 127;
        f16x8 ov;
        #pragma unroll
        for (int e = 0; e < 8; ++e) {
            int k = tile * 64 + w * 8 + e;
            int i = -1, j = 0;
            if (k < 16384)       { i = k & 127;   j = k >> 7;    }
            else if (k < 16512)  { i = 128;       j = k - 16384; }
            else if (k < 16640)  { i = k - 16512; j = 128;       }
            else if (k == 16640) { i = 128;       j = 128;       }
            float val = 0.f;
            if (i >= 0) val = T[(((size_t)a * 129 + i) * 129 + j) * 128 + col];
            ov[e] = (f16)val;
        }
        *(f16x8*)(base + (size_t)v * 8) = ov;
    }
}

__device__ __forceinline__ f16x8 pack_f16x8(f32x4 a, f32x4 b) {
    f16x8 h;
    #pragma unroll
    for (int e = 0; e < 4; ++e) { h[e] = (f16)a[e]; h[e + 4] = (f16)b[e]; }
    return h;
}

// ---------------------------------------------------------------------------
// GEMM, round 13: nf=4 (wave = 64 rows x 64 cols) halves af-build VALU per
// MFMA (the round-12 residual, VALUBusy 39%). BM=256, 8 waves (4M x 2N),
// grid 256 = 1 block/CU = 2 waves/SIMD; regs ~212 <= 256 cap (512,2) -> no
// spill. 16x16x32 MFMA, 16 acc chains/wave, 32 MFMA per j per wave.
// K split by (i-half, j-half): 16 classes (a,ihalf,jks), XCD-resident
// (1MB B-stream x 2 classes per XCD). Corrections as round 12.
// ---------------------------------------------------------------------------
template <bool ATOMIC>
__global__ __launch_bounds__(512, 2) void gemm_kernel(const float* __restrict__ x0,
                                                      const float* __restrict__ x1,
                                                      const f16* __restrict__ Tb,
                                                      float* __restrict__ dst) {
    __shared__ __align__(16) f16 h1t[64 * 256];     // 32KB: h1t[c][row], c = j - jb

    int bid = blockIdx.x;             // 256 = 8 xcd * 32
    int xcd = bid & 7, idx = bid >> 3;
    int cls = xcd * 2 + (idx >> 4);   // 16 classes, 2 per XCD
    int mt  = idx & 15;
    int a     = cls & 3;
    int ihalf = (cls >> 2) & 1;
    int jks   = cls >> 3;
    int b0 = mt * BM;
    int jb = jks * 64;

    int t    = threadIdx.x;
    int lane = t & 63, wid = t >> 6;
    int wm   = wid >> 1, wn = wid & 1;     // 4M x 2N
    int l15  = lane & 15, g = lane >> 4;   // 16x16 frag: row/col=l15, k-octet=g

    const char* tbb = (const char*)Tb + (size_t)a * NTILES * TILE_B;

    // ---- one-time h1 window (64 j, base jb) -> LDS transposed ----
    {
        int row = t & 255, part = t >> 8;            // 2 parts x 32 c
        const float* x1r = x1 + ((size_t)(b0 + row) * NA + a) * DDIM + jb + part * 32;
        #pragma unroll
        for (int q = 0; q < 8; ++q) {
            f32x4 v = *(const f32x4*)(x1r + q * 4);
            #pragma unroll
            for (int e = 0; e < 4; ++e)
                h1t[(part * 32 + q * 4 + e) * 256 + row] = (f16)v[e];
        }
    }
    // ---- one-time h0 -> registers: h0r[mf][s], i = ihalf*64 + s*32 + g*8 ----
    f16x8 h0r[4][2];
    #pragma unroll
    for (int mf = 0; mf < 4; ++mf) {
        int row = b0 + wm * 64 + mf * 16 + l15;
        const float* x0r = x0 + ((size_t)row * NA + a) * DDIM + ihalf * 64;
        #pragma unroll
        for (int s = 0; s < 2; ++s) {
            int ib = s * 32 + g * 8;
            h0r[mf][s] = pack_f16x8(*(const f32x4*)(x0r + ib),
                                    *(const f32x4*)(x0r + ib + 4));
        }
    }
    __syncthreads();   // h1t visible; only barrier in the kernel

    // per-lane B base: col = wn*64 + nf*16 + l15 (nf 0..3); octet = s*4+g
    const char* bp = tbb + ((size_t)g * 128 + wn * 64 + l15) * 16;
    #define BFOFF(nf, s) ((s) * 8192 + (nf) * 256)
    // main tile for j-index p (p in [0,64)): tile = 2*(jb+p) + ihalf
    #define TADR(p) (bp + (size_t)(2 * (jb + (p)) + ihalf) * TILE_B)

    f16x8 bA[8], bB[8];   // [nf*2+s], double-buffered over j parity
    {
        const char* q0 = TADR(0);
        const char* q1 = TADR(1);
        #pragma unroll
        for (int nf = 0; nf < 4; ++nf)
            #pragma unroll
            for (int s = 0; s < 2; ++s) {
                bA[nf * 2 + s] = *(const f16x8*)(q0 + BFOFF(nf, s));
                bB[nf * 2 + s] = *(const f16x8*)(q1 + BFOFF(nf, s));
            }
    }

    f32x4 acc[4][4];
    #pragma unroll
    for (int mf = 0; mf < 4; ++mf)
        #pragma unroll
        for (int nf = 0; nf < 4; ++nf) acc[mf][nf] = (f32x4)0.f;

    // ---- main loop: 64 j's as 32 pairs, barrier-free ----
    #pragma unroll 1
    for (int q = 0; q < 32; ++q) {
        int p0 = 2 * q, p1 = 2 * q + 1;
        f16 h1v0[4], h1v1[4];
        #pragma unroll
        for (int mf = 0; mf < 4; ++mf) {
            int row = wm * 64 + mf * 16 + l15;
            h1v0[mf] = h1t[p0 * 256 + row];
            h1v1[mf] = h1t[p1 * 256 + row];
        }

        // j = jb+p0 : 32-MFMA cluster from bA (each af feeds 4 MFMAs)
        __builtin_amdgcn_s_setprio(1);
        #pragma unroll
        for (int s = 0; s < 2; ++s)
            #pragma unroll
            for (int mf = 0; mf < 4; ++mf) {
                f16x8 af = h0r[mf][s] * h1v0[mf];
                #pragma unroll
                for (int nf = 0; nf < 4; ++nf)
                    acc[mf][nf] = __builtin_amdgcn_mfma_f32_16x16x32_f16(
                        af, bA[nf * 2 + s], acc[mf][nf], 0, 0, 0);
            }
        __builtin_amdgcn_s_setprio(0);
        {   // prefetch j-slot p0+2 into bA
            int np = p0 + 2; if (np > 63) np = 63;
            const char* qq = TADR(np);
            #pragma unroll
            for (int nf = 0; nf < 4; ++nf)
                #pragma unroll
                for (int s = 0; s < 2; ++s)
                    bA[nf * 2 + s] = *(const f16x8*)(qq + BFOFF(nf, s));
        }

        // j = jb+p1 : 32-MFMA cluster from bB
        __builtin_amdgcn_s_setprio(1);
        #pragma unroll
        for (int s = 0; s < 2; ++s)
            #pragma unroll
            for (int mf = 0; mf < 4; ++mf) {
                f16x8 af = h0r[mf][s] * h1v1[mf];
                #pragma unroll
                for (int nf = 0; nf < 4; ++nf)
                    acc[mf][nf] = __builtin_amdgcn_mfma_f32_16x16x32_f16(
                        af, bB[nf * 2 + s], acc[mf][nf], 0, 0, 0);
            }
        __builtin_amdgcn_s_setprio(0);
        {   // prefetch j-slot p1+2 into bB
            int np = p1 + 2; if (np > 63) np = 63;
            const char* qq = TADR(np);
            #pragma unroll
            for (int nf = 0; nf < 4; ++nf)
                #pragma unroll
                for (int s = 0; s < 2; ++s)
                    bB[nf * 2 + s] = *(const f16x8*)(qq + BFOFF(nf, s));
        }
    }

    // ---- correction tail per class ----
    int ct0, ct1, ncorr;
    if (ihalf == 0 && jks == 0)      { ct0 = 256; ct1 = 258; ncorr = 2; }
    else if (ihalf == 0 && jks == 1) { ct0 = 257; ct1 = 0;   ncorr = 1; }
    else if (ihalf == 1 && jks == 0) { ct0 = 259; ct1 = 0;   ncorr = 1; }
    else                             { ct0 = 260; ct1 = 0;   ncorr = 1; }
    for (int cc = 0; cc < ncorr; ++cc) {
        int tile = (cc == 0) ? ct0 : ct1;
        const char* qq = tbb + (size_t)tile * TILE_B
                       + ((size_t)g * 128 + wn * 64 + l15) * 16;
        f16x8 bt[8];
        #pragma unroll
        for (int nf = 0; nf < 4; ++nf)
            #pragma unroll
            for (int s = 0; s < 2; ++s)
                bt[nf * 2 + s] = *(const f16x8*)(qq + BFOFF(nf, s));

        #pragma unroll
        for (int s = 0; s < 2; ++s)
            #pragma unroll
            for (int mf = 0; mf < 4; ++mf) {
                int row = wm * 64 + mf * 16 + l15;
                f16x8 af;
                if (tile == 256 || tile == 257) {        // j-corr: G = h1[jb + c]
                    #pragma unroll
                    for (int e = 0; e < 8; ++e)
                        af[e] = h1t[(s * 32 + g * 8 + e) * 256 + row];
                } else if (tile == 258 || tile == 259) { // i-corr: G = h0[ihalf*64 + c]
                    af = h0r[mf][s];
                } else {                                 // 260: G = 1 at k_local 0
                    af = (f16x8)(f16)0.f;
                    if (s == 0 && g == 0) af[0] = (f16)1.f;
                }
                #pragma unroll
                for (int nf = 0; nf < 4; ++nf)
                    acc[mf][nf] = __builtin_amdgcn_mfma_f32_16x16x32_f16(
                        af, bt[nf * 2 + s], acc[mf][nf], 0, 0, 0);
            }
    }

    // ---- epilogue: 16x16 C/D layout col=lane&15, row=(lane>>4)*4+r ----
    int clsk = ihalf * 2 + jks;
    float* base = ATOMIC ? dst : dst + (size_t)clsk * OUT_ELEMS;
    #pragma unroll
    for (int mf = 0; mf < 4; ++mf)
        #pragma unroll
        for (int nf = 0; nf < 4; ++nf)
            #pragma unroll
            for (int r = 0; r < 4; ++r) {
                int orow = b0 + wm * 64 + mf * 16 + g * 4 + r;
                int ocol = wn * 64 + nf * 16 + l15;
                size_t off = ((size_t)orow * NA + a) * OUTD + ocol;
                if (ATOMIC) unsafeAtomicAdd(&base[off], acc[mf][nf][r]);
                else        base[off] = acc[mf][nf][r];
            }
    #undef BFOFF
    #undef TADR
}

// ---------------------------------------------------------------------------
// Reduce: out = P0 + P1 + P2 + P3 (f32x4 vectorized)
// ---------------------------------------------------------------------------
__global__ __launch_bounds__(256) void reduce_kernel(const float* __restrict__ P,
                                                     float* __restrict__ out) {
    int i = blockIdx.x * 256 + threadIdx.x;     // 524288 vec4 elems
    f32x4 s = ((const f32x4*)P)[i];
    #pragma unroll
    for (int k = 1; k < NKS; ++k)
        s += ((const f32x4*)(P + (size_t)k * OUT_ELEMS))[i];
    ((f32x4*)out)[i] = s;
}

// ---------------------------------------------------------------------------
// Fallback (ws too small): naive but correct f32 kernel.
// ---------------------------------------------------------------------------
__global__ __launch_bounds__(128) void fallback_kernel(const float* __restrict__ x0,
                                                       const float* __restrict__ x1,
                                                       const float* __restrict__ T,
                                                       float* __restrict__ out) {
    int ba = blockIdx.x;
    int b = ba >> 2, a = ba & 3;
    int o = threadIdx.x;
    const float* h0 = x0 + ((size_t)b * NA + a) * DDIM;
    const float* h1 = x1 + ((size_t)b * NA + a) * DDIM;
    float acc = 0.f;
    for (int i = 0; i < 129; ++i) {
        float h0i = (i < 128) ? h0[i] : 1.f;
        const float* Trow = T + (((size_t)a * 129 + i) * 129) * 128 + o;
        float part = 0.f;
        for (int j = 0; j < 129; ++j) {
            float h1j = (j < 128) ? h1[j] : 1.f;
            part += h1j * Trow[(size_t)j * 128];
        }
        acc += h0i * part;
    }
    out[((size_t)b * NA + a) * OUTD + o] = acc;
}

extern "C" void kernel_launch(void* const* d_in, const int* in_sizes, int n_in,
                              void* d_out, int out_size, void* d_ws, size_t ws_size,
                              hipStream_t stream) {
    const float* x0 = (const float*)d_in[0];
    const float* x1 = (const float*)d_in[1];
    const float* T  = (const float*)d_in[2];
    float* out = (float*)d_out;

    if (ws_size < TB_BYTES) {
        fallback_kernel<<<4096 * NA, 128, 0, stream>>>(x0, x1, T, out);
        return;
    }

    f16* Tb = (f16*)d_ws;
    prep_kernel<<<NA * NTILES, 256, 0, stream>>>(T, Tb);

    if (ws_size >= WS_NEED) {
        float* P = (float*)((char*)d_ws + TB_BYTES);
        gemm_kernel<false><<<256, 512, 0, stream>>>(x0, x1, Tb, P);
        reduce_kernel<<<OUT_ELEMS / 4 / 256, 256, 0, stream>>>(P, out);
    } else {
        hipMemsetAsync(d_out, 0, (size_t)out_size * sizeof(float), stream);
        gemm_kernel<true><<<256, 512, 0, stream>>>(x0, x1, Tb, out);
    }
}

// Round 14
// 90.661 us; speedup vs baseline: 2.2106x; 1.0097x over previous
//
#include <hip/hip_runtime.h>
#include <stdint.h>
#include <stddef.h>

// Problem: out[b,a,o] = sum_{i,j} h0[b,a,i] h1[b,a,j] T[a,i,j,o], h=concat(x,1)
// GEMM form: C[b,o] += G[b,k]*Tb[a,k,o]; main k=j*128+i (i,j<128); k=16384+c:
// G=h1[c]; k=16512+c: G=h0[c]; k=16640: G=1.
#define NA     4
#define DDIM   128
#define OUTD   128
#define BM     256
#define NTILES 261
#define TILE_B 16384          // 128 cols * 64 k * 2B (16KB per K64-tile image)
#define OUT_ELEMS (4096 * NA * OUTD)   // 2,097,152 f32
#define NKS    4              // (i-half, j-half) split -> 4 partials

typedef _Float16 f16;
typedef __attribute__((ext_vector_type(8)))  _Float16 f16x8;
typedef __attribute__((ext_vector_type(4)))  float    f32x4;

static const size_t TB_BYTES = (size_t)NA * NTILES * TILE_B;           // 17,104,896
static const size_t WS_NEED  = TB_BYTES + (size_t)NKS * OUT_ELEMS * 4; // ~50.7 MB

// ---------------------------------------------------------------------------
// Prep: T f32 -> Tb f16, per (a,tile) a 16KB image; unit v = w*128+col
// (w = k-octet 0..7) holds k = tile*64 + w*8 + e at output-col `col`.
// ---------------------------------------------------------------------------
__global__ __launch_bounds__(256) void prep_kernel(const float* __restrict__ T,
                                                   f16* __restrict__ Tb) {
    int blk  = blockIdx.x;            // a*NTILES + tile
    int a    = blk / NTILES;
    int tile = blk - a * NTILES;
    int t    = threadIdx.x;
    f16* base = Tb + (size_t)blk * (TILE_B / 2);
    #pragma unroll
    for (int u = 0; u < 4; ++u) {
        int v   = t + u * 256;
        int w   = v >> 7;
        int col = v & 127;
        f16x8 ov;
        #pragma unroll
        for (int e = 0; e < 8; ++e) {
            int k = tile * 64 + w * 8 + e;
            int i = -1, j = 0;
            if (k < 16384)       { i = k & 127;   j = k >> 7;    }
            else if (k < 16512)  { i = 128;       j = k - 16384; }
            else if (k < 16640)  { i = k - 16512; j = 128;       }
            else if (k == 16640) { i = 128;       j = 128;       }
            float val = 0.f;
            if (i >= 0) val = T[(((size_t)a * 129 + i) * 129 + j) * 128 + col];
            ov[e] = (f16)val;
        }
        *(f16x8*)(base + (size_t)v * 8) = ov;
    }
}

__device__ __forceinline__ f16x8 pack_f16x8(f32x4 a, f32x4 b) {
    f16x8 h;
    #pragma unroll
    for (int e = 0; e < 4; ++e) { h[e] = (f16)a[e]; h[e + 4] = (f16)b[e]; }
    return h;
}

// ---------------------------------------------------------------------------
// GEMM, round 14: round-13 geometry (nf=4, wave 64x64, 16x16x32 MFMA,
// 16 acc chains/wave, BM=256, 8 waves 4M x 2N, grid 256 = 1 block/CU)
// + 4-DEEP register prefetch ring b0..b3 (2 j-pairs in flight): load for
// j is issued 4 j's early -> reuse distance ~3 bursts >> L2 latency,
// removing the round-13 residual (un-hidden load latency per pair).
// ~220 unified regs, 2 waves/SIMD cap 256 -> no spill.
// ---------------------------------------------------------------------------
template <bool ATOMIC>
__global__ __launch_bounds__(512, 2) void gemm_kernel(const float* __restrict__ x0,
                                                      const float* __restrict__ x1,
                                                      const f16* __restrict__ Tb,
                                                      float* __restrict__ dst) {
    __shared__ __align__(16) f16 h1t[64 * 256];     // 32KB: h1t[c][row], c = j - jb

    int bid = blockIdx.x;             // 256 = 8 xcd * 32
    int xcd = bid & 7, idx = bid >> 3;
    int cls = xcd * 2 + (idx >> 4);   // 16 classes, 2 per XCD
    int mt  = idx & 15;
    int a     = cls & 3;
    int ihalf = (cls >> 2) & 1;
    int jks   = cls >> 3;
    int b0 = mt * BM;
    int jb = jks * 64;

    int t    = threadIdx.x;
    int lane = t & 63, wid = t >> 6;
    int wm   = wid >> 1, wn = wid & 1;     // 4M x 2N
    int l15  = lane & 15, g = lane >> 4;   // 16x16 frag: row/col=l15, k-octet=g

    const char* tbb = (const char*)Tb + (size_t)a * NTILES * TILE_B;

    // ---- one-time h1 window (64 j, base jb) -> LDS transposed ----
    {
        int row = t & 255, part = t >> 8;            // 2 parts x 32 c
        const float* x1r = x1 + ((size_t)(b0 + row) * NA + a) * DDIM + jb + part * 32;
        #pragma unroll
        for (int q = 0; q < 8; ++q) {
            f32x4 v = *(const f32x4*)(x1r + q * 4);
            #pragma unroll
            for (int e = 0; e < 4; ++e)
                h1t[(part * 32 + q * 4 + e) * 256 + row] = (f16)v[e];
        }
    }
    // ---- one-time h0 -> registers: h0r[mf][s], i = ihalf*64 + s*32 + g*8 ----
    f16x8 h0r[4][2];
    #pragma unroll
    for (int mf = 0; mf < 4; ++mf) {
        int row = b0 + wm * 64 + mf * 16 + l15;
        const float* x0r = x0 + ((size_t)row * NA + a) * DDIM + ihalf * 64;
        #pragma unroll
        for (int s = 0; s < 2; ++s) {
            int ib = s * 32 + g * 8;
            h0r[mf][s] = pack_f16x8(*(const f32x4*)(x0r + ib),
                                    *(const f32x4*)(x0r + ib + 4));
        }
    }
    __syncthreads();   // h1t visible; only barrier in the kernel

    // per-lane B base: col = wn*64 + nf*16 + l15 (nf 0..3); octet = s*4+g
    const char* bp = tbb + ((size_t)g * 128 + wn * 64 + l15) * 16;
    #define BFOFF(nf, s) ((s) * 8192 + (nf) * 256)
    // main tile for j-index p (p in [0,64)): tile = 2*(jb+p) + ihalf
    #define TADR(p) (bp + (size_t)(2 * (jb + (p)) + ihalf) * TILE_B)

    f16x8 bq0[8], bq1[8], bq2[8], bq3[8];   // 4-deep ring, [nf*2+s]

    #define LOADT(BUF, P)                                                   \
    {   int np_ = (P); if (np_ > 63) np_ = 63;                              \
        const char* qq_ = TADR(np_);                                        \
        _Pragma("unroll")                                                   \
        for (int nf = 0; nf < 4; ++nf)                                      \
            _Pragma("unroll")                                               \
            for (int s = 0; s < 2; ++s)                                     \
                BUF[nf * 2 + s] = *(const f16x8*)(qq_ + BFOFF(nf, s));      \
    }

    #define COMPJ(BUF, P)                                                   \
    {   f16 h1v_[4];                                                        \
        _Pragma("unroll")                                                   \
        for (int mf = 0; mf < 4; ++mf)                                      \
            h1v_[mf] = h1t[(P) * 256 + wm * 64 + mf * 16 + l15];            \
        __builtin_amdgcn_s_setprio(1);                                      \
        _Pragma("unroll")                                                   \
        for (int s = 0; s < 2; ++s)                                         \
            _Pragma("unroll")                                               \
            for (int mf = 0; mf < 4; ++mf) {                                \
                f16x8 af_ = h0r[mf][s] * h1v_[mf];                          \
                _Pragma("unroll")                                           \
                for (int nf = 0; nf < 4; ++nf)                              \
                    acc[mf][nf] = __builtin_amdgcn_mfma_f32_16x16x32_f16(   \
                        af_, BUF[nf * 2 + s], acc[mf][nf], 0, 0, 0);        \
            }                                                               \
        __builtin_amdgcn_s_setprio(0);                                      \
    }

    // prologue: fill the ring with j = 0..3
    LOADT(bq0, 0) LOADT(bq1, 1) LOADT(bq2, 2) LOADT(bq3, 3)

    f32x4 acc[4][4];
    #pragma unroll
    for (int mf = 0; mf < 4; ++mf)
        #pragma unroll
        for (int nf = 0; nf < 4; ++nf) acc[mf][nf] = (f32x4)0.f;

    // ---- main loop: 64 j's as 16 iterations of 4, 4-deep prefetch ----
    #pragma unroll 1
    for (int q = 0; q < 16; ++q) {
        int p0 = 4 * q;
        COMPJ(bq0, p0)     LOADT(bq0, p0 + 4)
        COMPJ(bq1, p0 + 1) LOADT(bq1, p0 + 5)
        COMPJ(bq2, p0 + 2) LOADT(bq2, p0 + 6)
        COMPJ(bq3, p0 + 3) LOADT(bq3, p0 + 7)
    }

    // ---- correction tail per class ----
    int ct0, ct1, ncorr;
    if (ihalf == 0 && jks == 0)      { ct0 = 256; ct1 = 258; ncorr = 2; }
    else if (ihalf == 0 && jks == 1) { ct0 = 257; ct1 = 0;   ncorr = 1; }
    else if (ihalf == 1 && jks == 0) { ct0 = 259; ct1 = 0;   ncorr = 1; }
    else                             { ct0 = 260; ct1 = 0;   ncorr = 1; }
    for (int cc = 0; cc < ncorr; ++cc) {
        int tile = (cc == 0) ? ct0 : ct1;
        const char* qq = tbb + (size_t)tile * TILE_B
                       + ((size_t)g * 128 + wn * 64 + l15) * 16;
        f16x8 bt[8];
        #pragma unroll
        for (int nf = 0; nf < 4; ++nf)
            #pragma unroll
            for (int s = 0; s < 2; ++s)
                bt[nf * 2 + s] = *(const f16x8*)(qq + BFOFF(nf, s));

        #pragma unroll
        for (int s = 0; s < 2; ++s)
            #pragma unroll
            for (int mf = 0; mf < 4; ++mf) {
                int row = wm * 64 + mf * 16 + l15;
                f16x8 af;
                if (tile == 256 || tile == 257) {        // j-corr: G = h1[jb + c]
                    #pragma unroll
                    for (int e = 0; e < 8; ++e)
                        af[e] = h1t[(s * 32 + g * 8 + e) * 256 + row];
                } else if (tile == 258 || tile == 259) { // i-corr: G = h0[ihalf*64 + c]
                    af = h0r[mf][s];
                } else {                                 // 260: G = 1 at k_local 0
                    af = (f16x8)(f16)0.f;
                    if (s == 0 && g == 0) af[0] = (f16)1.f;
                }
                #pragma unroll
                for (int nf = 0; nf < 4; ++nf)
                    acc[mf][nf] = __builtin_amdgcn_mfma_f32_16x16x32_f16(
                        af, bt[nf * 2 + s], acc[mf][nf], 0, 0, 0);
            }
    }

    // ---- epilogue: 16x16 C/D layout col=lane&15, row=(lane>>4)*4+r ----
    int clsk = ihalf * 2 + jks;
    float* base = ATOMIC ? dst : dst + (size_t)clsk * OUT_ELEMS;
    #pragma unroll
    for (int mf = 0; mf < 4; ++mf)
        #pragma unroll
        for (int nf = 0; nf < 4; ++nf)
            #pragma unroll
            for (int r = 0; r < 4; ++r) {
                int orow = b0 + wm * 64 + mf * 16 + g * 4 + r;
                int ocol = wn * 64 + nf * 16 + l15;
                size_t off = ((size_t)orow * NA + a) * OUTD + ocol;
                if (ATOMIC) unsafeAtomicAdd(&base[off], acc[mf][nf][r]);
                else        base[off] = acc[mf][nf][r];
            }
    #undef BFOFF
    #undef TADR
    #undef LOADT
    #undef COMPJ
}

// ---------------------------------------------------------------------------
// Reduce: out = P0 + P1 + P2 + P3 (f32x4 vectorized)
// ---------------------------------------------------------------------------
__global__ __launch_bounds__(256) void reduce_kernel(const float* __restrict__ P,
                                                     float* __restrict__ out) {
    int i = blockIdx.x * 256 + threadIdx.x;     // 524288 vec4 elems
    f32x4 s = ((const f32x4*)P)[i];
    #pragma unroll
    for (int k = 1; k < NKS; ++k)
        s += ((const f32x4*)(P + (size_t)k * OUT_ELEMS))[i];
    ((f32x4*)out)[i] = s;
}

// ---------------------------------------------------------------------------
// Fallback (ws too small): naive but correct f32 kernel.
// ---------------------------------------------------------------------------
__global__ __launch_bounds__(128) void fallback_kernel(const float* __restrict__ x0,
                                                       const float* __restrict__ x1,
                                                       const float* __restrict__ T,
                                                       float* __restrict__ out) {
    int ba = blockIdx.x;
    int b = ba >> 2, a = ba & 3;
    int o = threadIdx.x;
    const float* h0 = x0 + ((size_t)b * NA + a) * DDIM;
    const float* h1 = x1 + ((size_t)b * NA + a) * DDIM;
    float acc = 0.f;
    for (int i = 0; i < 129; ++i) {
        float h0i = (i < 128) ? h0[i] : 1.f;
        const float* Trow = T + (((size_t)a * 129 + i) * 129) * 128 + o;
        float part = 0.f;
        for (int j = 0; j < 129; ++j) {
            float h1j = (j < 128) ? h1[j] : 1.f;
            part += h1j * Trow[(size_t)j * 128];
        }
        acc += h0i * part;
    }
    out[((size_t)b * NA + a) * OUTD + o] = acc;
}

extern "C" void kernel_launch(void* const* d_in, const int* in_sizes, int n_in,
                              void* d_out, int out_size, void* d_ws, size_t ws_size,
                              hipStream_t stream) {
    const float* x0 = (const float*)d_in[0];
    const float* x1 = (const float*)d_in[1];
    const float* T  = (const float*)d_in[2];
    float* out = (float*)d_out;

    if (ws_size < TB_BYTES) {
        fallback_kernel<<<4096 * NA, 128, 0, stream>>>(x0, x1, T, out);
        return;
    }

    f16* Tb = (f16*)d_ws;
    prep_kernel<<<NA * NTILES, 256, 0, stream>>>(T, Tb);

    if (ws_size >= WS_NEED) {
        float* P = (float*)((char*)d_ws + TB_BYTES);
        gemm_kernel<false><<<256, 512, 0, stream>>>(x0, x1, Tb, P);
        reduce_kernel<<<OUT_ELEMS / 4 / 256, 256, 0, stream>>>(P, out);
    } else {
        hipMemsetAsync(d_out, 0, (size_t)out_size * sizeof(float), stream);
        gemm_kernel<true><<<256, 512, 0, stream>>>(x0, x1, Tb, out);
    }
}